// Round 2
// baseline (1880.571 us; speedup 1.0000x reference)
//
#include <hip/hip_runtime.h>

// ---------------- problem constants ----------------
#define NF   12
#define INV_TEMP 1.1785113019775793f   // 1 / max(sqrt(8)*0.3, 0.5)

// ---------------- ws layout (floats) ----------------
#define WS_ACC 0     // double accumulator (2 floats)
#define WS_WE2 2     // 384  folded embed (adj folded in)
#define WS_BE2 386   // 32   folded embed bias
#define WS_H1C 418   // 16   homeo layer-1 constant part
#define WS_QK  434   // 16   qk[r*8+d]
#define WS_QB  450   // 2
#define WS_WOT 452   // 96   W_out transposed [3][32]
#define WS_BD  548   // 8    basis row0 - row1
#define WS_B1  556   // 8    basis row1
#define WS_GW  564   // 8    gate_w
#define WS_GB  572   // 1
#define WS_BO  573   // 3    b_out
#define WS_LUT 576   // 4096 = 64x64 homeo LUT
#define WS_V   4672  // 32*nB  (16B aligned: 4672%4==0)

#define LUT_N     64
#define LUT_SCALE 15.75f   // 63/4 : domain [0,4]

// ---------------- helpers ----------------
__device__ __forceinline__ float fsig(float x)   { return 1.0f/(1.0f+__expf(-x)); }
__device__ __forceinline__ float fclip(float v,float lo,float hi){ return fminf(fmaxf(v,lo),hi); }
__device__ __forceinline__ void  fma4(float4&a,const float4&b,float s){ a.x+=b.x*s; a.y+=b.y*s; a.z+=b.z*s; a.w+=b.w*s; }
__device__ __forceinline__ float dot4(const float4&a,const float4&b){ return a.x*b.x+a.y*b.y+a.z*b.z+a.w*b.w; }
__device__ __forceinline__ float hsum4(const float4&a){ return a.x+a.y+a.z+a.w; }
__device__ __forceinline__ float4 clip4(float4 a,float lo,float hi){
  a.x=fclip(a.x,lo,hi); a.y=fclip(a.y,lo,hi); a.z=fclip(a.z,lo,hi); a.w=fclip(a.w,lo,hi); return a;
}

// ---------------- setup: fold constants into ws ----------------
__global__ void setup_k(const float* __restrict__ We,  const float* __restrict__ be,
                        const float* __restrict__ adjw,const float* __restrict__ Ww,
                        const float* __restrict__ w1,  const float* __restrict__ b1,
                        const float* __restrict__ basis,const float* __restrict__ qw,
                        const float* __restrict__ qb,  const float* __restrict__ kw,
                        const float* __restrict__ kb,  const float* __restrict__ Wo,
                        const float* __restrict__ gw,  const float* __restrict__ gb,
                        const float* __restrict__ bo,  float* __restrict__ ws)
{
  __shared__ float adj[16];
  __shared__ float K[16];
  const int t = threadIdx.x;
  if (t == 0) {
    const int mb[16] = {0,1,1,0, 1,0,0,1, 1,0,0,1, 0,1,1,0};
    for (int i=0;i<4;i++){
      float r[4]; float s=0.f;
      for (int j=0;j<4;j++){ float a = mb[i*4+j] ? fsig(adjw[i*4+j]) : 0.f; r[j]=a; s+=a; }
      s = fmaxf(s, 1e-6f);
      for (int j=0;j<4;j++) adj[i*4+j] = r[j]/s;
    }
    *reinterpret_cast<double*>(ws + WS_ACC) = 0.0;
    ws[WS_GB] = gb[0];
  }
  __syncthreads();
  for (int idx=t; idx<384; idx+=blockDim.x){
    int f=idx>>5, od=idx&31, i=od>>3, d=od&7;
    float s=0.f;
    for (int j=0;j<4;j++) s += adj[i*4+j]*We[f*32 + j*8 + d];
    ws[WS_WE2+idx]=s;
  }
  if (t < 32){
    int i=t>>3, d=t&7;
    float s=0.f;
    for (int j=0;j<4;j++) s += adj[i*4+j]*be[j*8 + d];
    ws[WS_BE2+t]=s;
  }
  if (t < 16){
    float s2=0.f;
    for (int k=0;k<64;k++) s2 += Ww[k]*Ww[k];
    float cf = sqrtf(s2);
    ws[WS_H1C+t] = cf*w1[32+t] + 0.5f*w1[48+t] + b1[t];
  }
  if (t < 16){
    int r=t>>3, e=t&7;
    float s=kb[e];
    for (int d=0;d<8;d++) s += basis[r*8+d]*kw[d*8+e];
    K[t]=s;
  }
  __syncthreads();
  if (t < 16){
    int r=t>>3, d=t&7;
    float s=0.f;
    for (int e=0;e<8;e++) s += qw[d*8+e]*K[r*8+e];
    ws[WS_QK+t]=s;
  }
  if (t < 2){
    float s=0.f;
    for (int e=0;e<8;e++) s += qb[e]*K[t*8+e];
    ws[WS_QB+t]=s;
  }
  if (t < 96){
    int c=t/32, od=t%32;
    ws[WS_WOT+t]=Wo[od*3+c];
  }
  if (t < 8){
    ws[WS_BD+t]=basis[t]-basis[8+t];
    ws[WS_B1+t]=basis[8+t];
    ws[WS_GW+t]=gw[t];
  }
  if (t < 3) ws[WS_BO+t]=bo[t];
}

// ---------------- LUT build: ctrl[:,2] = F(surprise, excitation) ----------------
__global__ void lut_k(const float* __restrict__ w1, const float* __restrict__ g,
                      const float* __restrict__ be, const float* __restrict__ w2,
                      const float* __restrict__ b2, const float* __restrict__ aw,
                      const float* __restrict__ ab, float* __restrict__ ws)
{
  const int idx = blockIdx.x*256 + threadIdx.x;
  if (idx >= LUT_N*LUT_N) return;
  const float s_in = (float)(idx>>6) * (4.0f/63.0f);
  const float e_in = (float)(idx&63) * (4.0f/63.0f);
  float h1[16]; float mu=0.f;
  #pragma unroll
  for (int k=0;k<16;k++){
    h1[k] = s_in*w1[k] + e_in*w1[16+k] + ws[WS_H1C+k];
    mu += h1[k];
  }
  mu *= 0.0625f;
  float var=0.f;
  #pragma unroll
  for (int k=0;k<16;k++){ float d=h1[k]-mu; var += d*d; }
  var *= 0.0625f;
  const float rs = rsqrtf(var + 1e-5f);
  float a[8];
  #pragma unroll
  for (int j=0;j<8;j++) a[j]=b2[j];
  #pragma unroll
  for (int k=0;k<16;k++){
    const float tk = tanhf((h1[k]-mu)*rs*g[k] + be[k]);
    #pragma unroll
    for (int j=0;j<8;j++) a[j] += tk*w2[k*8+j];
  }
  float ctl = ab[2];
  #pragma unroll
  for (int j=0;j<8;j++) ctl += fmaxf(a[j],0.f)*aw[j*4+2];
  ws[WS_LUT+idx] = 1.0f/(1.0f+expf(-ctl));
}

// ---------------- pass 1: gate reduction (+ optional v store) ----------------
template<bool STOREV>
__global__ __launch_bounds__(256,6) void pass1_k(
    const float* __restrict__ x,  const float* __restrict__ ws,
    const float* __restrict__ Vw, const float* __restrict__ Ww,
    double* __restrict__ acc, float* __restrict__ vout, int nB)
{
  __shared__ float4 sWE4[96];
  __shared__ float4 sBE4[8];
  __shared__ float4 sVw4[16];
  __shared__ float4 sWw4[16];
  __shared__ float  sLUT[4096];
  __shared__ double wsum[4];
  const int t = threadIdx.x;
  { float* p;
    p=(float*)sWE4; for (int i=t;i<384;i+=256) p[i]=ws[WS_WE2+i];
    p=(float*)sBE4; if (t<32) p[t]=ws[WS_BE2+t];
    p=(float*)sVw4; if (t<64) p[t]=Vw[t];
    p=(float*)sWw4; if (t<64) p[t]=Ww[t];
    for (int i=t;i<4096;i+=256) sLUT[i]=ws[WS_LUT+i];
  }
  __syncthreads();

  float csum = 0.f;
  for (int b = blockIdx.x*256 + t; b < nB; b += gridDim.x*256) {
    const float4* xp = reinterpret_cast<const float4*>(x + (size_t)b*NF);
    const float4 xa=xp[0], xb=xp[1], xc=xp[2];
    const float xv[12] = {xa.x,xa.y,xa.z,xa.w, xb.x,xb.y,xb.z,xb.w, xc.x,xc.y,xc.z,xc.w};
    #pragma unroll
    for (int i=0;i<4;i++){
      // h row for node i
      float4 h0=sBE4[2*i], h1=sBE4[2*i+1];
      #pragma unroll
      for (int f=0;f<12;f++){ fma4(h0,sWE4[f*8+2*i],xv[f]); fma4(h1,sWE4[f*8+2*i+1],xv[f]); }
      const float hr[8] = {h0.x,h0.y,h0.z,h0.w, h1.x,h1.y,h1.z,h1.w};
      // v = clip(h @ Vw)
      if (STOREV){
        float4 v0={0,0,0,0}, v1={0,0,0,0};
        #pragma unroll
        for (int d=0;d<8;d++){ fma4(v0,sVw4[2*d],hr[d]); fma4(v1,sVw4[2*d+1],hr[d]); }
        v0=clip4(v0,-2.f,2.f); v1=clip4(v1,-2.f,2.f);
        float4* vp = reinterpret_cast<float4*>(vout + (size_t)b*32 + i*8);
        vp[0]=v0; vp[1]=v1;
      }
      // surprise = |var(h_row)-0.5|
      float mu = (hsum4(h0)+hsum4(h1))*0.125f;
      float m2 = 0.f;
      #pragma unroll
      for (int d=0;d<8;d++){ float dd=hr[d]-mu; m2+=dd*dd; }
      const float sp = fabsf(m2*0.125f - 0.5f);
      // excitation = mean|h @ Ww|
      float4 e0={0,0,0,0}, e1={0,0,0,0};
      #pragma unroll
      for (int d=0;d<8;d++){ fma4(e0,sWw4[2*d],hr[d]); fma4(e1,sWw4[2*d+1],hr[d]); }
      const float exc = (fabsf(e0.x)+fabsf(e0.y)+fabsf(e0.z)+fabsf(e0.w)
                        +fabsf(e1.x)+fabsf(e1.y)+fabsf(e1.z)+fabsf(e1.w))*0.125f;
      // bilinear LUT
      const float fs = fminf(sp *LUT_SCALE, 62.999f);
      const float fe = fminf(exc*LUT_SCALE, 62.999f);
      const int i0=(int)fs, j0=(int)fe;
      const float ts=fs-(float)i0, te=fe-(float)j0;
      const float* Lp = &sLUT[i0*64+j0];
      const float v00=Lp[0], v01=Lp[1], v10=Lp[64], v11=Lp[65];
      const float r0 = v00 + ts*(v10-v00);
      const float r1 = v01 + ts*(v11-v01);
      csum += r0 + te*(r1-r0);
    }
  }
  #pragma unroll
  for (int off=32; off>0; off>>=1) csum += __shfl_down(csum, off, 64);
  if ((t&63)==0) wsum[t>>6] = (double)csum;
  __syncthreads();
  if (t==0) atomicAdd(acc, wsum[0]+wsum[1]+wsum[2]+wsum[3]);
}

// ---------------- pass 2: finish forward from v (or recompute) ----------------
template<bool RECOMP>
__global__ __launch_bounds__(256,6) void pass2_k(
    const float* __restrict__ x,  const float* __restrict__ ws,
    const float* __restrict__ Vw, const float* __restrict__ vin,
    float* __restrict__ out, int nB)
{
  __shared__ float4 sWE4[96];
  __shared__ float4 sBE4[8];
  __shared__ float4 sVw4[16];
  __shared__ float4 sQk4[4];
  __shared__ float4 sWoT4[24];
  __shared__ float4 sGw4[2];
  __shared__ float  sBD[8], sB1[8];
  __shared__ float  sGb, sQb[2], sBo[3], sGateVal;
  const int t = threadIdx.x;
  { float* p;
    if (RECOMP){
      p=(float*)sWE4; for (int i=t;i<384;i+=256) p[i]=ws[WS_WE2+i];
      p=(float*)sBE4; if (t<32) p[t]=ws[WS_BE2+t];
      p=(float*)sVw4; if (t<64) p[t]=Vw[t];
    }
    p=(float*)sQk4;  if (t<16) p[t]=ws[WS_QK+t];
    p=(float*)sWoT4; if (t<96) p[t]=ws[WS_WOT+t];
    p=(float*)sGw4;  if (t<8)  p[t]=ws[WS_GW+t];
    if (t<8){ sBD[t]=ws[WS_BD+t]; sB1[t]=ws[WS_B1+t]; }
    if (t<3) sBo[t]=ws[WS_BO+t];
    if (t==0){
      sGb=ws[WS_GB]; sQb[0]=ws[WS_QB]; sQb[1]=ws[WS_QB+1];
      sGateVal = (float)( *reinterpret_cast<const double*>(ws+WS_ACC) / (4.0*(double)nB) );
    }
  }
  __syncthreads();

  const float gateVal = sGateVal;
  for (int b = blockIdx.x*256 + t; b < nB; b += gridDim.x*256) {
    float4 vv[8];
    if (RECOMP){
      const float4* xp = reinterpret_cast<const float4*>(x + (size_t)b*NF);
      const float4 xa=xp[0], xb=xp[1], xc=xp[2];
      const float xv[12] = {xa.x,xa.y,xa.z,xa.w, xb.x,xb.y,xb.z,xb.w, xc.x,xc.y,xc.z,xc.w};
      #pragma unroll
      for (int i=0;i<4;i++){
        float4 h0=sBE4[2*i], h1=sBE4[2*i+1];
        #pragma unroll
        for (int f=0;f<12;f++){ fma4(h0,sWE4[f*8+2*i],xv[f]); fma4(h1,sWE4[f*8+2*i+1],xv[f]); }
        const float hr[8] = {h0.x,h0.y,h0.z,h0.w, h1.x,h1.y,h1.z,h1.w};
        float4 v0={0,0,0,0}, v1={0,0,0,0};
        #pragma unroll
        for (int d=0;d<8;d++){ fma4(v0,sVw4[2*d],hr[d]); fma4(v1,sVw4[2*d+1],hr[d]); }
        vv[2*i]  = clip4(v0,-2.f,2.f);
        vv[2*i+1]= clip4(v1,-2.f,2.f);
      }
    } else {
      const float4* vp = reinterpret_cast<const float4*>(vin + (size_t)b*32);
      #pragma unroll
      for (int o=0;o<8;o++) vv[o]=vp[o];
    }
    float lg0=sBo[0], lg1=sBo[1], lg2=sBo[2];
    #pragma unroll
    for (int i=0;i<4;i++){
      float4 v0=vv[2*i], v1=vv[2*i+1];
      const float gs = sGb + dot4(v0,sGw4[0]) + dot4(v1,sGw4[1]);
      const float gate = fsig(gs)*gateVal;
      const float4 c0 = clip4(make_float4(gate*v0.x,gate*v0.y,gate*v0.z,gate*v0.w),-2.f,2.f);
      const float4 c1 = clip4(make_float4(gate*v1.x,gate*v1.y,gate*v1.z,gate*v1.w),-2.f,2.f);
      float at0 = sQb[0] + dot4(c0,sQk4[0]) + dot4(c1,sQk4[1]);
      float at1 = sQb[1] + dot4(c0,sQk4[2]) + dot4(c1,sQk4[3]);
      at0 = fclip(at0*INV_TEMP,-5.f,5.f);
      at1 = fclip(at1*INV_TEMP,-5.f,5.f);
      const float w0 = fsig(at0-at1);
      float4 o0, o1;
      o0.x = fclip(sB1[0]+w0*sBD[0]+0.2f*c0.x, -2.f, 2.f);
      o0.y = fclip(sB1[1]+w0*sBD[1]+0.2f*c0.y, -2.f, 2.f);
      o0.z = fclip(sB1[2]+w0*sBD[2]+0.2f*c0.z, -2.f, 2.f);
      o0.w = fclip(sB1[3]+w0*sBD[3]+0.2f*c0.w, -2.f, 2.f);
      o1.x = fclip(sB1[4]+w0*sBD[4]+0.2f*c1.x, -2.f, 2.f);
      o1.y = fclip(sB1[5]+w0*sBD[5]+0.2f*c1.y, -2.f, 2.f);
      o1.z = fclip(sB1[6]+w0*sBD[6]+0.2f*c1.z, -2.f, 2.f);
      o1.w = fclip(sB1[7]+w0*sBD[7]+0.2f*c1.w, -2.f, 2.f);
      lg0 += dot4(o0,sWoT4[0*8+2*i]) + dot4(o1,sWoT4[0*8+2*i+1]);
      lg1 += dot4(o0,sWoT4[1*8+2*i]) + dot4(o1,sWoT4[1*8+2*i+1]);
      lg2 += dot4(o0,sWoT4[2*8+2*i]) + dot4(o1,sWoT4[2*8+2*i+1]);
    }
    out[(size_t)b*3+0]=lg0;
    out[(size_t)b*3+1]=lg1;
    out[(size_t)b*3+2]=lg2;
  }
}

// ---------------- launch ----------------
extern "C" void kernel_launch(void* const* d_in, const int* in_sizes, int n_in,
                              void* d_out, int out_size, void* d_ws, size_t ws_size,
                              hipStream_t stream)
{
  const float* x      = (const float*)d_in[0];
  const float* We     = (const float*)d_in[1];
  const float* be_    = (const float*)d_in[2];
  const float* adjw   = (const float*)d_in[3];
  const float* Vw     = (const float*)d_in[4];
  const float* Ww     = (const float*)d_in[5];
  const float* gate_w = (const float*)d_in[6];
  const float* gate_b = (const float*)d_in[7];
  const float* hc_w1  = (const float*)d_in[8];
  const float* hc_b1  = (const float*)d_in[9];
  const float* hc_g   = (const float*)d_in[10];
  const float* hc_be  = (const float*)d_in[11];
  const float* hc_w2  = (const float*)d_in[12];
  const float* hc_b2  = (const float*)d_in[13];
  const float* hc_aw  = (const float*)d_in[14];
  const float* hc_ab  = (const float*)d_in[15];
  const float* basis  = (const float*)d_in[16];
  const float* q_w    = (const float*)d_in[17];
  const float* q_b    = (const float*)d_in[18];
  const float* k_w    = (const float*)d_in[19];
  const float* k_b    = (const float*)d_in[20];
  const float* W_out  = (const float*)d_in[21];
  const float* b_out  = (const float*)d_in[22];

  float* ws  = (float*)d_ws;
  float* out = (float*)d_out;
  const int nB = in_sizes[0] / NF;

  setup_k<<<1, 256, 0, stream>>>(We, be_, adjw, Ww, hc_w1, hc_b1,
                                 basis, q_w, q_b, k_w, k_b, W_out,
                                 gate_w, gate_b, b_out, ws);
  lut_k<<<16, 256, 0, stream>>>(hc_w1, hc_g, hc_be, hc_w2, hc_b2,
                                hc_aw, hc_ab, ws);

  int blocks = (nB + 255) / 256;
  if (blocks > 2048) blocks = 2048;
  double* acc = (double*)(ws + WS_ACC);

  const size_t need = ((size_t)WS_V + (size_t)nB*32) * sizeof(float);
  if (ws_size >= need) {
    float* vbuf = ws + WS_V;
    pass1_k<true ><<<blocks, 256, 0, stream>>>(x, ws, Vw, Ww, acc, vbuf, nB);
    pass2_k<false><<<blocks, 256, 0, stream>>>(x, ws, Vw, vbuf, out, nB);
  } else {
    pass1_k<false><<<blocks, 256, 0, stream>>>(x, ws, Vw, Ww, acc, nullptr, nB);
    pass2_k<true ><<<blocks, 256, 0, stream>>>(x, ws, Vw, nullptr, out, nB);
  }
}

// Round 3
// 610.567 us; speedup vs baseline: 3.0800x; 3.0800x over previous
//
#include <hip/hip_runtime.h>

// ---------------- problem constants ----------------
#define NF   12
#define INV_TEMP 1.1785113019775793f   // 1 / max(sqrt(8)*0.3, 0.5)

// ---------------- ws layout (floats) ----------------
#define WS_ACC 0     // double accumulator (2 floats)
#define WS_WE2 2     // 384  folded embed (adj folded in)
#define WS_BE2 386   // 32   folded embed bias
#define WS_H1C 418   // 16   homeo layer-1 constant part
#define WS_QK  434   // 16   qk[r*8+d]
#define WS_QB  450   // 2
#define WS_WOT 452   // 96   W_out transposed [3][32]
#define WS_BD  548   // 8    basis row0 - row1
#define WS_B1  556   // 8    basis row1
#define WS_GW  564   // 8    gate_w
#define WS_GB  572   // 1
#define WS_BO  573   // 3    b_out
#define WS_LUT 576   // 4096 = 64x64 homeo LUT
#define WS_V   4672  // 32*nB

#define LUT_N     64
#define LUT_SCALE 15.75f   // 63/4 : domain [0,4]

// ---------------- helpers ----------------
__device__ __forceinline__ float fsig(float x)   { return 1.0f/(1.0f+__expf(-x)); }
__device__ __forceinline__ float fclip(float v,float lo,float hi){ return fminf(fmaxf(v,lo),hi); }
__device__ __forceinline__ void  fma4(float4&a,const float4&b,float s){ a.x+=b.x*s; a.y+=b.y*s; a.z+=b.z*s; a.w+=b.w*s; }
__device__ __forceinline__ float dot4(const float4&a,const float4&b){ return a.x*b.x+a.y*b.y+a.z*b.z+a.w*b.w; }
__device__ __forceinline__ float hsum4(const float4&a){ return a.x+a.y+a.z+a.w; }
__device__ __forceinline__ float4 clip4(float4 a,float lo,float hi){
  a.x=fclip(a.x,lo,hi); a.y=fclip(a.y,lo,hi); a.z=fclip(a.z,lo,hi); a.w=fclip(a.w,lo,hi); return a;
}

// ---------------- setup: fold constants into ws ----------------
__global__ void setup_k(const float* __restrict__ We,  const float* __restrict__ be,
                        const float* __restrict__ adjw,const float* __restrict__ Ww,
                        const float* __restrict__ w1,  const float* __restrict__ b1,
                        const float* __restrict__ basis,const float* __restrict__ qw,
                        const float* __restrict__ qb,  const float* __restrict__ kw,
                        const float* __restrict__ kb,  const float* __restrict__ Wo,
                        const float* __restrict__ gw,  const float* __restrict__ gb,
                        const float* __restrict__ bo,  float* __restrict__ ws)
{
  __shared__ float adj[16];
  __shared__ float K[16];
  const int t = threadIdx.x;
  if (t == 0) {
    const int mb[16] = {0,1,1,0, 1,0,0,1, 1,0,0,1, 0,1,1,0};
    for (int i=0;i<4;i++){
      float r[4]; float s=0.f;
      for (int j=0;j<4;j++){ float a = mb[i*4+j] ? fsig(adjw[i*4+j]) : 0.f; r[j]=a; s+=a; }
      s = fmaxf(s, 1e-6f);
      for (int j=0;j<4;j++) adj[i*4+j] = r[j]/s;
    }
    *reinterpret_cast<double*>(ws + WS_ACC) = 0.0;
    ws[WS_GB] = gb[0];
  }
  __syncthreads();
  for (int idx=t; idx<384; idx+=blockDim.x){
    int f=idx>>5, od=idx&31, i=od>>3, d=od&7;
    float s=0.f;
    for (int j=0;j<4;j++) s += adj[i*4+j]*We[f*32 + j*8 + d];
    ws[WS_WE2+idx]=s;
  }
  if (t < 32){
    int i=t>>3, d=t&7;
    float s=0.f;
    for (int j=0;j<4;j++) s += adj[i*4+j]*be[j*8 + d];
    ws[WS_BE2+t]=s;
  }
  if (t < 16){
    float s2=0.f;
    for (int k=0;k<64;k++) s2 += Ww[k]*Ww[k];
    float cf = sqrtf(s2);
    ws[WS_H1C+t] = cf*w1[32+t] + 0.5f*w1[48+t] + b1[t];
  }
  if (t < 16){
    int r=t>>3, e=t&7;
    float s=kb[e];
    for (int d=0;d<8;d++) s += basis[r*8+d]*kw[d*8+e];
    K[t]=s;
  }
  __syncthreads();
  if (t < 16){
    int r=t>>3, d=t&7;
    float s=0.f;
    for (int e=0;e<8;e++) s += qw[d*8+e]*K[r*8+e];
    ws[WS_QK+t]=s;
  }
  if (t < 2){
    float s=0.f;
    for (int e=0;e<8;e++) s += qb[e]*K[t*8+e];
    ws[WS_QB+t]=s;
  }
  if (t < 96){
    int c=t/32, od=t%32;
    ws[WS_WOT+t]=Wo[od*3+c];
  }
  if (t < 8){
    ws[WS_BD+t]=basis[t]-basis[8+t];
    ws[WS_B1+t]=basis[8+t];
    ws[WS_GW+t]=gw[t];
  }
  if (t < 3) ws[WS_BO+t]=bo[t];
}

// ---------------- LUT build: ctrl[:,2] = F(surprise, excitation) ----------------
__global__ void lut_k(const float* __restrict__ w1, const float* __restrict__ g,
                      const float* __restrict__ be, const float* __restrict__ w2,
                      const float* __restrict__ b2, const float* __restrict__ aw,
                      const float* __restrict__ ab, float* __restrict__ ws)
{
  const int idx = blockIdx.x*256 + threadIdx.x;
  if (idx >= LUT_N*LUT_N) return;
  const float s_in = (float)(idx>>6) * (4.0f/63.0f);
  const float e_in = (float)(idx&63) * (4.0f/63.0f);
  float h1[16]; float mu=0.f;
  #pragma unroll
  for (int k=0;k<16;k++){
    h1[k] = s_in*w1[k] + e_in*w1[16+k] + ws[WS_H1C+k];
    mu += h1[k];
  }
  mu *= 0.0625f;
  float var=0.f;
  #pragma unroll
  for (int k=0;k<16;k++){ float d=h1[k]-mu; var += d*d; }
  var *= 0.0625f;
  const float rs = rsqrtf(var + 1e-5f);
  float a[8];
  #pragma unroll
  for (int j=0;j<8;j++) a[j]=b2[j];
  #pragma unroll
  for (int k=0;k<16;k++){
    const float tk = tanhf((h1[k]-mu)*rs*g[k] + be[k]);
    #pragma unroll
    for (int j=0;j<8;j++) a[j] += tk*w2[k*8+j];
  }
  float ctl = ab[2];
  #pragma unroll
  for (int j=0;j<8;j++) ctl += fmaxf(a[j],0.f)*aw[j*4+2];
  ws[WS_LUT+idx] = 1.0f/(1.0f+expf(-ctl));
}

// ---------------- pass 1: gate reduction (+ v store) ----------------
template<bool STOREV>
__global__ __launch_bounds__(256,2) void pass1_k(
    const float* __restrict__ x,  const float* __restrict__ ws,
    const float* __restrict__ Vw, const float* __restrict__ Ww,
    double* __restrict__ acc, float* __restrict__ vout, int nB)
{
  __shared__ float4 sWE4[96];
  __shared__ float4 sBE4[8];
  __shared__ float4 sVw4[16];
  __shared__ float4 sWw4[16];
  __shared__ float  sLUT[4096];
  __shared__ double wsum[4];
  const int t = threadIdx.x;
  { float* p;
    p=(float*)sWE4; for (int i=t;i<384;i+=256) p[i]=ws[WS_WE2+i];
    p=(float*)sBE4; if (t<32) p[t]=ws[WS_BE2+t];
    p=(float*)sVw4; if (t<64) p[t]=Vw[t];
    p=(float*)sWw4; if (t<64) p[t]=Ww[t];
    for (int i=t;i<4096;i+=256) sLUT[i]=ws[WS_LUT+i];
  }
  __syncthreads();

  float csum = 0.f;
  for (int b = blockIdx.x*256 + t; b < nB; b += gridDim.x*256) {
    const float4* xp = reinterpret_cast<const float4*>(x + (size_t)b*NF);
    const float4 xa=xp[0], xb=xp[1], xc=xp[2];
    const float xv[12] = {xa.x,xa.y,xa.z,xa.w, xb.x,xb.y,xb.z,xb.w, xc.x,xc.y,xc.z,xc.w};
    #pragma unroll
    for (int i=0;i<4;i++){
      float4 h0=sBE4[2*i], h1=sBE4[2*i+1];
      #pragma unroll
      for (int f=0;f<12;f++){ fma4(h0,sWE4[f*8+2*i],xv[f]); fma4(h1,sWE4[f*8+2*i+1],xv[f]); }
      const float hr[8] = {h0.x,h0.y,h0.z,h0.w, h1.x,h1.y,h1.z,h1.w};
      if (STOREV){
        float4 v0={0,0,0,0}, v1={0,0,0,0};
        #pragma unroll
        for (int d=0;d<8;d++){ fma4(v0,sVw4[2*d],hr[d]); fma4(v1,sVw4[2*d+1],hr[d]); }
        v0=clip4(v0,-2.f,2.f); v1=clip4(v1,-2.f,2.f);
        float4* vp = reinterpret_cast<float4*>(vout + (size_t)b*32 + i*8);
        vp[0]=v0; vp[1]=v1;
      }
      float mu = (hsum4(h0)+hsum4(h1))*0.125f;
      float m2 = 0.f;
      #pragma unroll
      for (int d=0;d<8;d++){ float dd=hr[d]-mu; m2+=dd*dd; }
      const float sp = fabsf(m2*0.125f - 0.5f);
      float4 e0={0,0,0,0}, e1={0,0,0,0};
      #pragma unroll
      for (int d=0;d<8;d++){ fma4(e0,sWw4[2*d],hr[d]); fma4(e1,sWw4[2*d+1],hr[d]); }
      const float exc = (fabsf(e0.x)+fabsf(e0.y)+fabsf(e0.z)+fabsf(e0.w)
                        +fabsf(e1.x)+fabsf(e1.y)+fabsf(e1.z)+fabsf(e1.w))*0.125f;
      const float fs = fminf(sp *LUT_SCALE, 62.999f);
      const float fe = fminf(exc*LUT_SCALE, 62.999f);
      const int i0=(int)fs, j0=(int)fe;
      const float ts=fs-(float)i0, te=fe-(float)j0;
      const float* Lp = &sLUT[i0*64+j0];
      const float v00=Lp[0], v01=Lp[1], v10=Lp[64], v11=Lp[65];
      const float r0 = v00 + ts*(v10-v00);
      const float r1 = v01 + ts*(v11-v01);
      csum += r0 + te*(r1-r0);
    }
  }
  #pragma unroll
  for (int off=32; off>0; off>>=1) csum += __shfl_down(csum, off, 64);
  if ((t&63)==0) wsum[t>>6] = (double)csum;
  __syncthreads();
  if (t==0) atomicAdd(acc, wsum[0]+wsum[1]+wsum[2]+wsum[3]);
}

// ---------------- pass 2: finish forward from v (or recompute) ----------------
template<bool RECOMP>
__global__ __launch_bounds__(256,2) void pass2_k(
    const float* __restrict__ x,  const float* __restrict__ ws,
    const float* __restrict__ Vw, const float* __restrict__ vin,
    float* __restrict__ out, int nB)
{
  __shared__ float4 sWE4[96];
  __shared__ float4 sBE4[8];
  __shared__ float4 sVw4[16];
  __shared__ float4 sQk4[4];
  __shared__ float4 sWoT4[24];
  __shared__ float4 sGw4[2];
  __shared__ float  sBD[8], sB1[8];
  __shared__ float  sGb, sQb[2], sBo[3], sGateVal;
  const int t = threadIdx.x;
  { float* p;
    if (RECOMP){
      p=(float*)sWE4; for (int i=t;i<384;i+=256) p[i]=ws[WS_WE2+i];
      p=(float*)sBE4; if (t<32) p[t]=ws[WS_BE2+t];
      p=(float*)sVw4; if (t<64) p[t]=Vw[t];
    }
    p=(float*)sQk4;  if (t<16) p[t]=ws[WS_QK+t];
    p=(float*)sWoT4; if (t<96) p[t]=ws[WS_WOT+t];
    p=(float*)sGw4;  if (t<8)  p[t]=ws[WS_GW+t];
    if (t<8){ sBD[t]=ws[WS_BD+t]; sB1[t]=ws[WS_B1+t]; }
    if (t<3) sBo[t]=ws[WS_BO+t];
    if (t==0){
      sGb=ws[WS_GB]; sQb[0]=ws[WS_QB]; sQb[1]=ws[WS_QB+1];
      sGateVal = (float)( *reinterpret_cast<const double*>(ws+WS_ACC) / (4.0*(double)nB) );
    }
  }
  __syncthreads();

  const float gateVal = sGateVal;
  for (int b = blockIdx.x*256 + t; b < nB; b += gridDim.x*256) {
    float4 vv[8];
    if (RECOMP){
      const float4* xp = reinterpret_cast<const float4*>(x + (size_t)b*NF);
      const float4 xa=xp[0], xb=xp[1], xc=xp[2];
      const float xv[12] = {xa.x,xa.y,xa.z,xa.w, xb.x,xb.y,xb.z,xb.w, xc.x,xc.y,xc.z,xc.w};
      #pragma unroll
      for (int i=0;i<4;i++){
        float4 h0=sBE4[2*i], h1=sBE4[2*i+1];
        #pragma unroll
        for (int f=0;f<12;f++){ fma4(h0,sWE4[f*8+2*i],xv[f]); fma4(h1,sWE4[f*8+2*i+1],xv[f]); }
        const float hr[8] = {h0.x,h0.y,h0.z,h0.w, h1.x,h1.y,h1.z,h1.w};
        float4 v0={0,0,0,0}, v1={0,0,0,0};
        #pragma unroll
        for (int d=0;d<8;d++){ fma4(v0,sVw4[2*d],hr[d]); fma4(v1,sVw4[2*d+1],hr[d]); }
        vv[2*i]  = clip4(v0,-2.f,2.f);
        vv[2*i+1]= clip4(v1,-2.f,2.f);
      }
    } else {
      const float4* vp = reinterpret_cast<const float4*>(vin + (size_t)b*32);
      #pragma unroll
      for (int o=0;o<8;o++) vv[o]=vp[o];
    }
    float lg0=sBo[0], lg1=sBo[1], lg2=sBo[2];
    #pragma unroll
    for (int i=0;i<4;i++){
      float4 v0=vv[2*i], v1=vv[2*i+1];
      const float gs = sGb + dot4(v0,sGw4[0]) + dot4(v1,sGw4[1]);
      const float gate = fsig(gs)*gateVal;
      const float4 c0 = clip4(make_float4(gate*v0.x,gate*v0.y,gate*v0.z,gate*v0.w),-2.f,2.f);
      const float4 c1 = clip4(make_float4(gate*v1.x,gate*v1.y,gate*v1.z,gate*v1.w),-2.f,2.f);
      float at0 = sQb[0] + dot4(c0,sQk4[0]) + dot4(c1,sQk4[1]);
      float at1 = sQb[1] + dot4(c0,sQk4[2]) + dot4(c1,sQk4[3]);
      at0 = fclip(at0*INV_TEMP,-5.f,5.f);
      at1 = fclip(at1*INV_TEMP,-5.f,5.f);
      const float w0 = fsig(at0-at1);
      float4 o0, o1;
      o0.x = fclip(sB1[0]+w0*sBD[0]+0.2f*c0.x, -2.f, 2.f);
      o0.y = fclip(sB1[1]+w0*sBD[1]+0.2f*c0.y, -2.f, 2.f);
      o0.z = fclip(sB1[2]+w0*sBD[2]+0.2f*c0.z, -2.f, 2.f);
      o0.w = fclip(sB1[3]+w0*sBD[3]+0.2f*c0.w, -2.f, 2.f);
      o1.x = fclip(sB1[4]+w0*sBD[4]+0.2f*c1.x, -2.f, 2.f);
      o1.y = fclip(sB1[5]+w0*sBD[5]+0.2f*c1.y, -2.f, 2.f);
      o1.z = fclip(sB1[6]+w0*sBD[6]+0.2f*c1.z, -2.f, 2.f);
      o1.w = fclip(sB1[7]+w0*sBD[7]+0.2f*c1.w, -2.f, 2.f);
      lg0 += dot4(o0,sWoT4[0*8+2*i]) + dot4(o1,sWoT4[0*8+2*i+1]);
      lg1 += dot4(o0,sWoT4[1*8+2*i]) + dot4(o1,sWoT4[1*8+2*i+1]);
      lg2 += dot4(o0,sWoT4[2*8+2*i]) + dot4(o1,sWoT4[2*8+2*i+1]);
    }
    out[(size_t)b*3+0]=lg0;
    out[(size_t)b*3+1]=lg1;
    out[(size_t)b*3+2]=lg2;
  }
}

// ---------------- launch ----------------
extern "C" void kernel_launch(void* const* d_in, const int* in_sizes, int n_in,
                              void* d_out, int out_size, void* d_ws, size_t ws_size,
                              hipStream_t stream)
{
  const float* x      = (const float*)d_in[0];
  const float* We     = (const float*)d_in[1];
  const float* be_    = (const float*)d_in[2];
  const float* adjw   = (const float*)d_in[3];
  const float* Vw     = (const float*)d_in[4];
  const float* Ww     = (const float*)d_in[5];
  const float* gate_w = (const float*)d_in[6];
  const float* gate_b = (const float*)d_in[7];
  const float* hc_w1  = (const float*)d_in[8];
  const float* hc_b1  = (const float*)d_in[9];
  const float* hc_g   = (const float*)d_in[10];
  const float* hc_be  = (const float*)d_in[11];
  const float* hc_w2  = (const float*)d_in[12];
  const float* hc_b2  = (const float*)d_in[13];
  const float* hc_aw  = (const float*)d_in[14];
  const float* hc_ab  = (const float*)d_in[15];
  const float* basis  = (const float*)d_in[16];
  const float* q_w    = (const float*)d_in[17];
  const float* q_b    = (const float*)d_in[18];
  const float* k_w    = (const float*)d_in[19];
  const float* k_b    = (const float*)d_in[20];
  const float* W_out  = (const float*)d_in[21];
  const float* b_out  = (const float*)d_in[22];

  float* ws  = (float*)d_ws;
  float* out = (float*)d_out;
  const int nB = in_sizes[0] / NF;

  setup_k<<<1, 256, 0, stream>>>(We, be_, adjw, Ww, hc_w1, hc_b1,
                                 basis, q_w, q_b, k_w, k_b, W_out,
                                 gate_w, gate_b, b_out, ws);
  lut_k<<<16, 256, 0, stream>>>(hc_w1, hc_g, hc_be, hc_w2, hc_b2,
                                hc_aw, hc_ab, ws);

  int blocks = (nB + 255) / 256;
  if (blocks > 2048) blocks = 2048;
  double* acc = (double*)(ws + WS_ACC);

  const size_t need = ((size_t)WS_V + (size_t)nB*32) * sizeof(float);
  if (ws_size >= need) {
    float* vbuf = ws + WS_V;
    pass1_k<true ><<<blocks, 256, 0, stream>>>(x, ws, Vw, Ww, acc, vbuf, nB);
    pass2_k<false><<<blocks, 256, 0, stream>>>(x, ws, Vw, vbuf, out, nB);
  } else {
    pass1_k<false><<<blocks, 256, 0, stream>>>(x, ws, Vw, Ww, acc, nullptr, nB);
    pass2_k<true ><<<blocks, 256, 0, stream>>>(x, ws, Vw, nullptr, out, nB);
  }
}

// Round 4
// 265.114 us; speedup vs baseline: 7.0934x; 2.3030x over previous
//
#include <hip/hip_runtime.h>

// ---------------- problem constants ----------------
#define NF   12
#define INV_TEMP 1.1785113019775793f   // 1 / max(sqrt(8)*0.3, 0.5)

// ---------------- ws layout (floats) ----------------
#define WS_ACC 0     // double accumulator (2 floats)
#define WS_WE2 2     // 384  folded embed (adj folded in)
#define WS_BE2 386   // 32   folded embed bias
#define WS_H1C 418   // 16   homeo layer-1 constant part
#define WS_QK  434   // 16   qk[r*8+d] (pre-scaled by INV_TEMP)
#define WS_QB  450   // 2    (pre-scaled by INV_TEMP)
#define WS_WOT 452   // 96   W_out transposed [3][32]
#define WS_BD  548   // 8    basis row0 - row1
#define WS_B1  556   // 8    basis row1
#define WS_GW  564   // 8    gate_w
#define WS_GB  572   // 1
#define WS_BO  573   // 3    b_out
#define WS_LUT 576   // 4096 = 64x64 homeo LUT

#define LUT_N     64
#define LUT_SCALE 15.75f   // 63/4 : domain [0,4]

// ---------------- helpers ----------------
__device__ __forceinline__ float fsig(float x)   { return 1.0f/(1.0f+__expf(-x)); }
__device__ __forceinline__ float fclip(float v,float lo,float hi){ return fminf(fmaxf(v,lo),hi); }
__device__ __forceinline__ void  fma4(float4&a,const float4&b,float s){ a.x+=b.x*s; a.y+=b.y*s; a.z+=b.z*s; a.w+=b.w*s; }
__device__ __forceinline__ float dot4(const float4&a,const float4&b){ return a.x*b.x+a.y*b.y+a.z*b.z+a.w*b.w; }
__device__ __forceinline__ float hsum4(const float4&a){ return a.x+a.y+a.z+a.w; }
__device__ __forceinline__ float4 clip4(float4 a,float lo,float hi){
  a.x=fclip(a.x,lo,hi); a.y=fclip(a.y,lo,hi); a.z=fclip(a.z,lo,hi); a.w=fclip(a.w,lo,hi); return a;
}

// ---------------- setup: fold constants into ws ----------------
__global__ void setup_k(const float* __restrict__ We,  const float* __restrict__ be,
                        const float* __restrict__ adjw,const float* __restrict__ Ww,
                        const float* __restrict__ w1,  const float* __restrict__ b1,
                        const float* __restrict__ basis,const float* __restrict__ qw,
                        const float* __restrict__ qb,  const float* __restrict__ kw,
                        const float* __restrict__ kb,  const float* __restrict__ Wo,
                        const float* __restrict__ gw,  const float* __restrict__ gb,
                        const float* __restrict__ bo,  float* __restrict__ ws)
{
  __shared__ float adj[16];
  __shared__ float K[16];
  const int t = threadIdx.x;
  if (t == 0) {
    const int mb[16] = {0,1,1,0, 1,0,0,1, 1,0,0,1, 0,1,1,0};
    for (int i=0;i<4;i++){
      float r[4]; float s=0.f;
      for (int j=0;j<4;j++){ float a = mb[i*4+j] ? fsig(adjw[i*4+j]) : 0.f; r[j]=a; s+=a; }
      s = fmaxf(s, 1e-6f);
      for (int j=0;j<4;j++) adj[i*4+j] = r[j]/s;
    }
    *reinterpret_cast<double*>(ws + WS_ACC) = 0.0;
    ws[WS_GB] = gb[0];
  }
  __syncthreads();
  for (int idx=t; idx<384; idx+=blockDim.x){
    int f=idx>>5, od=idx&31, i=od>>3, d=od&7;
    float s=0.f;
    for (int j=0;j<4;j++) s += adj[i*4+j]*We[f*32 + j*8 + d];
    ws[WS_WE2+idx]=s;
  }
  if (t < 32){
    int i=t>>3, d=t&7;
    float s=0.f;
    for (int j=0;j<4;j++) s += adj[i*4+j]*be[j*8 + d];
    ws[WS_BE2+t]=s;
  }
  if (t < 16){
    float s2=0.f;
    for (int k=0;k<64;k++) s2 += Ww[k]*Ww[k];
    float cf = sqrtf(s2);
    ws[WS_H1C+t] = cf*w1[32+t] + 0.5f*w1[48+t] + b1[t];
  }
  if (t < 16){
    int r=t>>3, e=t&7;
    float s=kb[e];
    for (int d=0;d<8;d++) s += basis[r*8+d]*kw[d*8+e];
    K[t]=s;
  }
  __syncthreads();
  if (t < 16){
    int r=t>>3, d=t&7;
    float s=0.f;
    for (int e=0;e<8;e++) s += qw[d*8+e]*K[r*8+e];
    ws[WS_QK+t]=s*INV_TEMP;
  }
  if (t < 2){
    float s=0.f;
    for (int e=0;e<8;e++) s += qb[e]*K[t*8+e];
    ws[WS_QB+t]=s*INV_TEMP;
  }
  if (t < 96){
    int c=t/32, od=t%32;
    ws[WS_WOT+t]=Wo[od*3+c];
  }
  if (t < 8){
    ws[WS_BD+t]=basis[t]-basis[8+t];
    ws[WS_B1+t]=basis[8+t];
    ws[WS_GW+t]=gw[t];
  }
  if (t < 3) ws[WS_BO+t]=bo[t];
}

// ---------------- LUT build: ctrl[:,2] = F(surprise, excitation) ----------------
__global__ void lut_k(const float* __restrict__ w1, const float* __restrict__ g,
                      const float* __restrict__ be, const float* __restrict__ w2,
                      const float* __restrict__ b2, const float* __restrict__ aw,
                      const float* __restrict__ ab, float* __restrict__ ws)
{
  const int idx = blockIdx.x*256 + threadIdx.x;
  if (idx >= LUT_N*LUT_N) return;
  const float s_in = (float)(idx>>6) * (4.0f/63.0f);
  const float e_in = (float)(idx&63) * (4.0f/63.0f);
  float h1[16]; float mu=0.f;
  #pragma unroll
  for (int k=0;k<16;k++){
    h1[k] = s_in*w1[k] + e_in*w1[16+k] + ws[WS_H1C+k];
    mu += h1[k];
  }
  mu *= 0.0625f;
  float var=0.f;
  #pragma unroll
  for (int k=0;k<16;k++){ float d=h1[k]-mu; var += d*d; }
  var *= 0.0625f;
  const float rs = rsqrtf(var + 1e-5f);
  float a[8];
  #pragma unroll
  for (int j=0;j<8;j++) a[j]=b2[j];
  #pragma unroll
  for (int k=0;k<16;k++){
    const float tk = tanhf((h1[k]-mu)*rs*g[k] + be[k]);
    #pragma unroll
    for (int j=0;j<8;j++) a[j] += tk*w2[k*8+j];
  }
  float ctl = ab[2];
  #pragma unroll
  for (int j=0;j<8;j++) ctl += fmaxf(a[j],0.f)*aw[j*4+2];
  ws[WS_LUT+idx] = 1.0f/(1.0f+expf(-ctl));
}

// ---------------- pass 1: gate reduction only ----------------
__global__ __launch_bounds__(256,2) void pass1_k(
    const float* __restrict__ x,  const float* __restrict__ ws,
    const float* __restrict__ Ww, double* __restrict__ acc, int nB)
{
  __shared__ float4 sWE4[96];
  __shared__ float4 sBE4[8];
  __shared__ float4 sWw4[16];
  __shared__ float  sLUT[4096];
  __shared__ double wsum[4];
  const int t = threadIdx.x;
  { float* p;
    p=(float*)sWE4; for (int i=t;i<384;i+=256) p[i]=ws[WS_WE2+i];
    p=(float*)sBE4; if (t<32) p[t]=ws[WS_BE2+t];
    p=(float*)sWw4; if (t<64) p[t]=Ww[t];
    float4* L4 = reinterpret_cast<float4*>(sLUT);
    const float4* W4 = reinterpret_cast<const float4*>(ws + WS_LUT);
    for (int i=t;i<1024;i+=256) L4[i]=W4[i];
  }
  __syncthreads();

  float csum = 0.f;
  const int b = blockIdx.x*256 + t;
  if (b < nB) {
    const float4* xp = reinterpret_cast<const float4*>(x + (size_t)b*NF);
    const float4 xa=xp[0], xb=xp[1], xc=xp[2];
    const float xv[12] = {xa.x,xa.y,xa.z,xa.w, xb.x,xb.y,xb.z,xb.w, xc.x,xc.y,xc.z,xc.w};
    #pragma unroll
    for (int i=0;i<4;i++){
      float4 h0=sBE4[2*i], h1=sBE4[2*i+1];
      #pragma unroll
      for (int f=0;f<12;f++){ fma4(h0,sWE4[f*8+2*i],xv[f]); fma4(h1,sWE4[f*8+2*i+1],xv[f]); }
      const float hr[8] = {h0.x,h0.y,h0.z,h0.w, h1.x,h1.y,h1.z,h1.w};
      float mu = (hsum4(h0)+hsum4(h1))*0.125f;
      float m2 = 0.f;
      #pragma unroll
      for (int d=0;d<8;d++){ float dd=hr[d]-mu; m2+=dd*dd; }
      const float sp = fabsf(m2*0.125f - 0.5f);
      float4 e0={0,0,0,0}, e1={0,0,0,0};
      #pragma unroll
      for (int d=0;d<8;d++){ fma4(e0,sWw4[2*d],hr[d]); fma4(e1,sWw4[2*d+1],hr[d]); }
      const float exc = (fabsf(e0.x)+fabsf(e0.y)+fabsf(e0.z)+fabsf(e0.w)
                        +fabsf(e1.x)+fabsf(e1.y)+fabsf(e1.z)+fabsf(e1.w))*0.125f;
      const float fs = fminf(sp *LUT_SCALE, 62.999f);
      const float fe = fminf(exc*LUT_SCALE, 62.999f);
      const int i0=(int)fs, j0=(int)fe;
      const float ts=fs-(float)i0, te=fe-(float)j0;
      const float* Lp = &sLUT[i0*64+j0];
      const float v00=Lp[0], v01=Lp[1], v10=Lp[64], v11=Lp[65];
      const float r0 = v00 + ts*(v10-v00);
      const float r1 = v01 + ts*(v11-v01);
      csum += r0 + te*(r1-r0);
    }
  }
  #pragma unroll
  for (int off=32; off>0; off>>=1) csum += __shfl_down(csum, off, 64);
  if ((t&63)==0) wsum[t>>6] = (double)csum;
  __syncthreads();
  if (t==0) atomicAdd(acc, wsum[0]+wsum[1]+wsum[2]+wsum[3]);
}

// ---------------- pass 2: full forward from x, write logits ----------------
__global__ __launch_bounds__(256,2) void pass2_k(
    const float* __restrict__ x,  const float* __restrict__ ws,
    const float* __restrict__ Vw, float* __restrict__ out, int nB)
{
  __shared__ float4 sWE4[96];
  __shared__ float4 sBE4[8];
  __shared__ float4 sVw4[16];
  __shared__ float4 sQk4[4];
  __shared__ float4 sWoT4[24];
  __shared__ float4 sGw4[2];
  __shared__ float  sBD[8], sB1[8];
  __shared__ float  sGb, sQb[2], sBo[3], sGateVal;
  const int t = threadIdx.x;
  { float* p;
    p=(float*)sWE4;  for (int i=t;i<384;i+=256) p[i]=ws[WS_WE2+i];
    p=(float*)sBE4;  if (t<32) p[t]=ws[WS_BE2+t];
    p=(float*)sVw4;  if (t<64) p[t]=Vw[t];
    p=(float*)sQk4;  if (t<16) p[t]=ws[WS_QK+t];
    p=(float*)sWoT4; if (t<96) p[t]=ws[WS_WOT+t];
    p=(float*)sGw4;  if (t<8)  p[t]=ws[WS_GW+t];
    if (t<8){ sBD[t]=ws[WS_BD+t]; sB1[t]=ws[WS_B1+t]; }
    if (t<3) sBo[t]=ws[WS_BO+t];
    if (t==0){
      sGb=ws[WS_GB]; sQb[0]=ws[WS_QB]; sQb[1]=ws[WS_QB+1];
      sGateVal = (float)( *reinterpret_cast<const double*>(ws+WS_ACC) / (4.0*(double)nB) );
    }
  }
  __syncthreads();

  const int b = blockIdx.x*256 + t;
  if (b >= nB) return;
  const float gateVal = sGateVal;
  const float4* xp = reinterpret_cast<const float4*>(x + (size_t)b*NF);
  const float4 xa=xp[0], xb=xp[1], xc=xp[2];
  const float xv[12] = {xa.x,xa.y,xa.z,xa.w, xb.x,xb.y,xb.z,xb.w, xc.x,xc.y,xc.z,xc.w};
  float lg0=sBo[0], lg1=sBo[1], lg2=sBo[2];
  #pragma unroll
  for (int i=0;i<4;i++){
    float4 h0=sBE4[2*i], h1=sBE4[2*i+1];
    #pragma unroll
    for (int f=0;f<12;f++){ fma4(h0,sWE4[f*8+2*i],xv[f]); fma4(h1,sWE4[f*8+2*i+1],xv[f]); }
    const float hr[8] = {h0.x,h0.y,h0.z,h0.w, h1.x,h1.y,h1.z,h1.w};
    float4 v0={0,0,0,0}, v1={0,0,0,0};
    #pragma unroll
    for (int d=0;d<8;d++){ fma4(v0,sVw4[2*d],hr[d]); fma4(v1,sVw4[2*d+1],hr[d]); }
    v0 = clip4(v0,-2.f,2.f); v1 = clip4(v1,-2.f,2.f);
    const float gs = sGb + dot4(v0,sGw4[0]) + dot4(v1,sGw4[1]);
    const float gate = fsig(gs)*gateVal;
    const float4 c0 = clip4(make_float4(gate*v0.x,gate*v0.y,gate*v0.z,gate*v0.w),-2.f,2.f);
    const float4 c1 = clip4(make_float4(gate*v1.x,gate*v1.y,gate*v1.z,gate*v1.w),-2.f,2.f);
    float at0 = sQb[0] + dot4(c0,sQk4[0]) + dot4(c1,sQk4[1]);
    float at1 = sQb[1] + dot4(c0,sQk4[2]) + dot4(c1,sQk4[3]);
    at0 = fclip(at0,-5.f,5.f);
    at1 = fclip(at1,-5.f,5.f);
    const float w0 = fsig(at0-at1);
    float4 o0, o1;
    o0.x = fclip(sB1[0]+w0*sBD[0]+0.2f*c0.x, -2.f, 2.f);
    o0.y = fclip(sB1[1]+w0*sBD[1]+0.2f*c0.y, -2.f, 2.f);
    o0.z = fclip(sB1[2]+w0*sBD[2]+0.2f*c0.z, -2.f, 2.f);
    o0.w = fclip(sB1[3]+w0*sBD[3]+0.2f*c0.w, -2.f, 2.f);
    o1.x = fclip(sB1[4]+w0*sBD[4]+0.2f*c1.x, -2.f, 2.f);
    o1.y = fclip(sB1[5]+w0*sBD[5]+0.2f*c1.y, -2.f, 2.f);
    o1.z = fclip(sB1[6]+w0*sBD[6]+0.2f*c1.z, -2.f, 2.f);
    o1.w = fclip(sB1[7]+w0*sBD[7]+0.2f*c1.w, -2.f, 2.f);
    lg0 += dot4(o0,sWoT4[0*8+2*i]) + dot4(o1,sWoT4[0*8+2*i+1]);
    lg1 += dot4(o0,sWoT4[1*8+2*i]) + dot4(o1,sWoT4[1*8+2*i+1]);
    lg2 += dot4(o0,sWoT4[2*8+2*i]) + dot4(o1,sWoT4[2*8+2*i+1]);
  }
  out[(size_t)b*3+0]=lg0;
  out[(size_t)b*3+1]=lg1;
  out[(size_t)b*3+2]=lg2;
}

// ---------------- launch ----------------
extern "C" void kernel_launch(void* const* d_in, const int* in_sizes, int n_in,
                              void* d_out, int out_size, void* d_ws, size_t ws_size,
                              hipStream_t stream)
{
  const float* x      = (const float*)d_in[0];
  const float* We     = (const float*)d_in[1];
  const float* be_    = (const float*)d_in[2];
  const float* adjw   = (const float*)d_in[3];
  const float* Vw     = (const float*)d_in[4];
  const float* Ww     = (const float*)d_in[5];
  const float* gate_w = (const float*)d_in[6];
  const float* gate_b = (const float*)d_in[7];
  const float* hc_w1  = (const float*)d_in[8];
  const float* hc_b1  = (const float*)d_in[9];
  const float* hc_g   = (const float*)d_in[10];
  const float* hc_be  = (const float*)d_in[11];
  const float* hc_w2  = (const float*)d_in[12];
  const float* hc_b2  = (const float*)d_in[13];
  const float* hc_aw  = (const float*)d_in[14];
  const float* hc_ab  = (const float*)d_in[15];
  const float* basis  = (const float*)d_in[16];
  const float* q_w    = (const float*)d_in[17];
  const float* q_b    = (const float*)d_in[18];
  const float* k_w    = (const float*)d_in[19];
  const float* k_b    = (const float*)d_in[20];
  const float* W_out  = (const float*)d_in[21];
  const float* b_out  = (const float*)d_in[22];

  float* ws  = (float*)d_ws;
  float* out = (float*)d_out;
  const int nB = in_sizes[0] / NF;

  setup_k<<<1, 256, 0, stream>>>(We, be_, adjw, Ww, hc_w1, hc_b1,
                                 basis, q_w, q_b, k_w, k_b, W_out,
                                 gate_w, gate_b, b_out, ws);
  lut_k<<<16, 256, 0, stream>>>(hc_w1, hc_g, hc_be, hc_w2, hc_b2,
                                hc_aw, hc_ab, ws);

  const int blocks = (nB + 255) / 256;
  double* acc = (double*)(ws + WS_ACC);

  pass1_k<<<blocks, 256, 0, stream>>>(x, ws, Ww, acc, nB);
  pass2_k<<<blocks, 256, 0, stream>>>(x, ws, Vw, out, nB);
}

// Round 5
// 167.064 us; speedup vs baseline: 11.2566x; 1.5869x over previous
//
#include <hip/hip_runtime.h>

// ---------------- problem constants ----------------
#define NF   12
#define INV_TEMP 1.1785113019775793f   // 1 / max(sqrt(8)*0.3, 0.5)

// ---------------- ws layout (floats) ----------------
#define WS_WE2 2     // 384  folded embed (adj folded in)
#define WS_BE2 386   // 32   folded embed bias
#define WS_QK  434   // 16   qk[r*8+d] (pre-scaled by INV_TEMP)
#define WS_QB  450   // 2    (pre-scaled by INV_TEMP)
#define WS_WOT 452   // 96   W_out transposed [3][32]
#define WS_BD  548   // 8    basis row0 - row1
#define WS_B1  556   // 8    basis row1
#define WS_GW  564   // 8    gate_w
#define WS_GB  572   // 1
#define WS_BO  573   // 3    b_out
#define WS_LUT 576   // 4096 = 64x64 homeo LUT
#define WS_PART 4672 // partial sums (doubles), float-offset (8B aligned)

#define LUT_N     64
#define LUT_SCALE 15.75f   // 63/4 : domain [0,4]

// ---------------- helpers ----------------
__device__ __forceinline__ float fsig(float x)   { return 1.0f/(1.0f+__expf(-x)); }
__device__ __forceinline__ float fclip(float v,float lo,float hi){ return fminf(fmaxf(v,lo),hi); }
__device__ __forceinline__ void  fma4(float4&a,const float4&b,float s){ a.x+=b.x*s; a.y+=b.y*s; a.z+=b.z*s; a.w+=b.w*s; }
__device__ __forceinline__ float dot4(const float4&a,const float4&b){ return a.x*b.x+a.y*b.y+a.z*b.z+a.w*b.w; }
__device__ __forceinline__ float hsum4(const float4&a){ return a.x+a.y+a.z+a.w; }
__device__ __forceinline__ float4 clip4(float4 a,float lo,float hi){
  a.x=fclip(a.x,lo,hi); a.y=fclip(a.y,lo,hi); a.z=fclip(a.z,lo,hi); a.w=fclip(a.w,lo,hi); return a;
}

// ---------------- setup + LUT (fused, 16 blocks) ----------------
__global__ void setup_k(const float* __restrict__ We,  const float* __restrict__ be,
                        const float* __restrict__ adjw,const float* __restrict__ Ww,
                        const float* __restrict__ w1,  const float* __restrict__ b1,
                        const float* __restrict__ g,   const float* __restrict__ be2,
                        const float* __restrict__ w2,  const float* __restrict__ b2,
                        const float* __restrict__ aw,  const float* __restrict__ ab,
                        const float* __restrict__ basis,const float* __restrict__ qw,
                        const float* __restrict__ qb,  const float* __restrict__ kw,
                        const float* __restrict__ kb,  const float* __restrict__ Wo,
                        const float* __restrict__ gw,  const float* __restrict__ gb,
                        const float* __restrict__ bo,  float* __restrict__ ws)
{
  __shared__ float adj[16];
  __shared__ float K[16];
  __shared__ float h1c[16];
  const int t = threadIdx.x;
  // every block: homeo layer-1 constant (cheap, redundant per block)
  if (t < 16){
    float s2=0.f;
    for (int k=0;k<64;k++) s2 += Ww[k]*Ww[k];
    const float cf = sqrtf(s2);
    h1c[t] = cf*w1[32+t] + 0.5f*w1[48+t] + b1[t];
  }
  if (blockIdx.x == 0){
    if (t == 0){
      const int mb[16] = {0,1,1,0, 1,0,0,1, 1,0,0,1, 0,1,1,0};
      for (int i=0;i<4;i++){
        float r[4]; float s=0.f;
        for (int j=0;j<4;j++){ float a = mb[i*4+j] ? fsig(adjw[i*4+j]) : 0.f; r[j]=a; s+=a; }
        s = fmaxf(s, 1e-6f);
        for (int j=0;j<4;j++) adj[i*4+j] = r[j]/s;
      }
      ws[WS_GB] = gb[0];
    }
    if (t < 16){
      int r=t>>3, e=t&7;
      float s=kb[e];
      for (int d=0;d<8;d++) s += basis[r*8+d]*kw[d*8+e];
      K[t]=s;
    }
  }
  __syncthreads();
  if (blockIdx.x == 0){
    for (int idx=t; idx<384; idx+=256){
      int f=idx>>5, od=idx&31, i=od>>3, d=od&7;
      float s=0.f;
      for (int j=0;j<4;j++) s += adj[i*4+j]*We[f*32 + j*8 + d];
      ws[WS_WE2+idx]=s;
    }
    if (t < 32){
      int i=t>>3, d=t&7;
      float s=0.f;
      for (int j=0;j<4;j++) s += adj[i*4+j]*be[j*8 + d];
      ws[WS_BE2+t]=s;
    }
    if (t < 16){
      int r=t>>3, d=t&7;
      float s=0.f;
      for (int e=0;e<8;e++) s += qw[d*8+e]*K[r*8+e];
      ws[WS_QK+t]=s*INV_TEMP;
    }
    if (t < 2){
      float s=0.f;
      for (int e=0;e<8;e++) s += qb[e]*K[t*8+e];
      ws[WS_QB+t]=s*INV_TEMP;
    }
    if (t < 96){
      int c=t/32, od=t%32;
      ws[WS_WOT+t]=Wo[od*3+c];
    }
    if (t < 8){
      ws[WS_BD+t]=basis[t]-basis[8+t];
      ws[WS_B1+t]=basis[8+t];
      ws[WS_GW+t]=gw[t];
    }
    if (t < 3) ws[WS_BO+t]=bo[t];
  }
  // every block: 256 LUT entries
  const int idx = blockIdx.x*256 + t;
  const float s_in = (float)(idx>>6) * (4.0f/63.0f);
  const float e_in = (float)(idx&63) * (4.0f/63.0f);
  float h1[16]; float mu=0.f;
  #pragma unroll
  for (int k=0;k<16;k++){
    h1[k] = s_in*w1[k] + e_in*w1[16+k] + h1c[k];
    mu += h1[k];
  }
  mu *= 0.0625f;
  float var=0.f;
  #pragma unroll
  for (int k=0;k<16;k++){ float d=h1[k]-mu; var += d*d; }
  var *= 0.0625f;
  const float rs = rsqrtf(var + 1e-5f);
  float a[8];
  #pragma unroll
  for (int j=0;j<8;j++) a[j]=b2[j];
  #pragma unroll
  for (int k=0;k<16;k++){
    const float tk = tanhf((h1[k]-mu)*rs*g[k] + be2[k]);
    #pragma unroll
    for (int j=0;j<8;j++) a[j] += tk*w2[k*8+j];
  }
  float ctl = ab[2];
  #pragma unroll
  for (int j=0;j<8;j++) ctl += fmaxf(a[j],0.f)*aw[j*4+2];
  ws[WS_LUT+idx] = 1.0f/(1.0f+expf(-ctl));
}

// ---------------- pass 1: per-block partial of gate sum ----------------
__global__ __launch_bounds__(256) void pass1_k(
    const float* __restrict__ x,  const float* __restrict__ ws,
    const float* __restrict__ Ww, double* __restrict__ part, int nB)
{
  __shared__ float4 sWE4[96];
  __shared__ float4 sBE4[8];
  __shared__ float4 sWw4[16];
  __shared__ float  sLUT[4096];
  __shared__ double wsum[4];
  const int t = threadIdx.x;
  { float* p;
    p=(float*)sWE4; for (int i=t;i<384;i+=256) p[i]=ws[WS_WE2+i];
    p=(float*)sBE4; if (t<32) p[t]=ws[WS_BE2+t];
    p=(float*)sWw4; if (t<64) p[t]=Ww[t];
    float4* L4 = reinterpret_cast<float4*>(sLUT);
    const float4* W4 = reinterpret_cast<const float4*>(ws + WS_LUT);
    for (int i=t;i<1024;i+=256) L4[i]=W4[i];
  }
  __syncthreads();

  const int base = blockIdx.x*512;
  const int b0 = base + t, b1 = base + 256 + t;
  const bool ok0 = b0 < nB, ok1 = b1 < nB;
  float4 x0a={0,0,0,0},x0b=x0a,x0c=x0a, x1a=x0a,x1b=x0a,x1c=x0a;
  if (ok0){ const float4* xp = reinterpret_cast<const float4*>(x + (size_t)b0*NF); x0a=xp[0]; x0b=xp[1]; x0c=xp[2]; }
  if (ok1){ const float4* xp = reinterpret_cast<const float4*>(x + (size_t)b1*NF); x1a=xp[0]; x1b=xp[1]; x1c=xp[2]; }
  const float xv0[12] = {x0a.x,x0a.y,x0a.z,x0a.w, x0b.x,x0b.y,x0b.z,x0b.w, x0c.x,x0c.y,x0c.z,x0c.w};
  const float xv1[12] = {x1a.x,x1a.y,x1a.z,x1a.w, x1b.x,x1b.y,x1b.z,x1b.w, x1c.x,x1c.y,x1c.z,x1c.w};

  float csum0 = 0.f, csum1 = 0.f;
  #pragma unroll
  for (int i=0;i<4;i++){
    float4 hA0=sBE4[2*i], hB0=sBE4[2*i+1];
    float4 hA1=hA0,       hB1=hB0;
    #pragma unroll
    for (int f=0;f<12;f++){
      const float4 w0=sWE4[f*8+2*i], w1=sWE4[f*8+2*i+1];
      fma4(hA0,w0,xv0[f]); fma4(hB0,w1,xv0[f]);
      fma4(hA1,w0,xv1[f]); fma4(hB1,w1,xv1[f]);
    }
    const float hr0[8] = {hA0.x,hA0.y,hA0.z,hA0.w, hB0.x,hB0.y,hB0.z,hB0.w};
    const float hr1[8] = {hA1.x,hA1.y,hA1.z,hA1.w, hB1.x,hB1.y,hB1.z,hB1.w};
    // surprise
    const float mu0 = (hsum4(hA0)+hsum4(hB0))*0.125f;
    const float mu1 = (hsum4(hA1)+hsum4(hB1))*0.125f;
    float m20=0.f, m21=0.f;
    #pragma unroll
    for (int d=0;d<8;d++){ float a=hr0[d]-mu0; m20+=a*a; float b=hr1[d]-mu1; m21+=b*b; }
    const float sp0 = fabsf(m20*0.125f - 0.5f);
    const float sp1 = fabsf(m21*0.125f - 0.5f);
    // excitation
    float4 eA0={0,0,0,0}, eB0=eA0, eA1=eA0, eB1=eA0;
    #pragma unroll
    for (int d=0;d<8;d++){
      const float4 wA=sWw4[2*d], wB=sWw4[2*d+1];
      fma4(eA0,wA,hr0[d]); fma4(eB0,wB,hr0[d]);
      fma4(eA1,wA,hr1[d]); fma4(eB1,wB,hr1[d]);
    }
    const float ex0 = (fabsf(eA0.x)+fabsf(eA0.y)+fabsf(eA0.z)+fabsf(eA0.w)
                      +fabsf(eB0.x)+fabsf(eB0.y)+fabsf(eB0.z)+fabsf(eB0.w))*0.125f;
    const float ex1 = (fabsf(eA1.x)+fabsf(eA1.y)+fabsf(eA1.z)+fabsf(eA1.w)
                      +fabsf(eB1.x)+fabsf(eB1.y)+fabsf(eB1.z)+fabsf(eB1.w))*0.125f;
    // bilinear LUT, both samples
    {
      const float fs = fminf(sp0*LUT_SCALE, 62.999f);
      const float fe = fminf(ex0*LUT_SCALE, 62.999f);
      const int i0=(int)fs, j0=(int)fe;
      const float ts=fs-(float)i0, te=fe-(float)j0;
      const float* Lp = &sLUT[i0*64+j0];
      const float v00=Lp[0], v01=Lp[1], v10=Lp[64], v11=Lp[65];
      const float r0 = v00 + ts*(v10-v00);
      const float r1 = v01 + ts*(v11-v01);
      if (ok0) csum0 += r0 + te*(r1-r0);
    }
    {
      const float fs = fminf(sp1*LUT_SCALE, 62.999f);
      const float fe = fminf(ex1*LUT_SCALE, 62.999f);
      const int i0=(int)fs, j0=(int)fe;
      const float ts=fs-(float)i0, te=fe-(float)j0;
      const float* Lp = &sLUT[i0*64+j0];
      const float v00=Lp[0], v01=Lp[1], v10=Lp[64], v11=Lp[65];
      const float r0 = v00 + ts*(v10-v00);
      const float r1 = v01 + ts*(v11-v01);
      if (ok1) csum1 += r0 + te*(r1-r0);
    }
  }
  float csum = csum0 + csum1;
  #pragma unroll
  for (int off=32; off>0; off>>=1) csum += __shfl_down(csum, off, 64);
  if ((t&63)==0) wsum[t>>6] = (double)csum;
  __syncthreads();
  if (t==0) part[blockIdx.x] = wsum[0]+wsum[1]+wsum[2]+wsum[3];
}

// ---------------- pass 2: reduce partials, full forward, write logits ----------------
__global__ __launch_bounds__(256) void pass2_k(
    const float* __restrict__ x,  const float* __restrict__ ws,
    const float* __restrict__ Vw, const double* __restrict__ part,
    float* __restrict__ out, int nB, int nblk)
{
  __shared__ float4 sWE4[96];
  __shared__ float4 sBE4[8];
  __shared__ float4 sVw4[16];
  __shared__ float4 sQk4[4];
  __shared__ float4 sWoT4[24];
  __shared__ float4 sGw4[2];
  __shared__ float  sBD[8], sB1[8];
  __shared__ float  sGb, sQb[2], sBo[3], sGateVal;
  __shared__ double red[4];
  const int t = threadIdx.x;
  // reduce partials (every block, deterministic)
  double dsum = 0.0;
  for (int i=t; i<nblk; i+=256) dsum += part[i];
  #pragma unroll
  for (int off=32; off>0; off>>=1) dsum += __shfl_down(dsum, off, 64);
  if ((t&63)==0) red[t>>6] = dsum;
  { float* p;
    p=(float*)sWE4;  for (int i=t;i<384;i+=256) p[i]=ws[WS_WE2+i];
    p=(float*)sBE4;  if (t<32) p[t]=ws[WS_BE2+t];
    p=(float*)sVw4;  if (t<64) p[t]=Vw[t];
    p=(float*)sQk4;  if (t<16) p[t]=ws[WS_QK+t];
    p=(float*)sWoT4; if (t<96) p[t]=ws[WS_WOT+t];
    p=(float*)sGw4;  if (t<8)  p[t]=ws[WS_GW+t];
    if (t<8){ sBD[t]=ws[WS_BD+t]; sB1[t]=ws[WS_B1+t]; }
    if (t<3) sBo[t]=ws[WS_BO+t];
    if (t==0){ sGb=ws[WS_GB]; sQb[0]=ws[WS_QB]; sQb[1]=ws[WS_QB+1]; }
  }
  __syncthreads();
  if (t==0) sGateVal = (float)((red[0]+red[1]+red[2]+red[3]) / (4.0*(double)nB));
  __syncthreads();

  const float gateVal = sGateVal;
  const int base = blockIdx.x*512;

  #pragma unroll
  for (int s=0;s<2;s++){
    const int b = base + s*256 + t;
    if (b >= nB) continue;
    const float4* xp = reinterpret_cast<const float4*>(x + (size_t)b*NF);
    const float4 xa=xp[0], xb=xp[1], xc=xp[2];
    const float xv[12] = {xa.x,xa.y,xa.z,xa.w, xb.x,xb.y,xb.z,xb.w, xc.x,xc.y,xc.z,xc.w};
    float lg0=sBo[0], lg1=sBo[1], lg2=sBo[2];
    #pragma unroll
    for (int i=0;i<4;i++){
      float4 h0=sBE4[2*i], h1=sBE4[2*i+1];
      #pragma unroll
      for (int f=0;f<12;f++){ fma4(h0,sWE4[f*8+2*i],xv[f]); fma4(h1,sWE4[f*8+2*i+1],xv[f]); }
      const float hr[8] = {h0.x,h0.y,h0.z,h0.w, h1.x,h1.y,h1.z,h1.w};
      float4 v0={0,0,0,0}, v1={0,0,0,0};
      #pragma unroll
      for (int d=0;d<8;d++){ fma4(v0,sVw4[2*d],hr[d]); fma4(v1,sVw4[2*d+1],hr[d]); }
      v0 = clip4(v0,-2.f,2.f); v1 = clip4(v1,-2.f,2.f);
      const float gs = sGb + dot4(v0,sGw4[0]) + dot4(v1,sGw4[1]);
      const float gate = fsig(gs)*gateVal;
      const float4 c0 = clip4(make_float4(gate*v0.x,gate*v0.y,gate*v0.z,gate*v0.w),-2.f,2.f);
      const float4 c1 = clip4(make_float4(gate*v1.x,gate*v1.y,gate*v1.z,gate*v1.w),-2.f,2.f);
      float at0 = sQb[0] + dot4(c0,sQk4[0]) + dot4(c1,sQk4[1]);
      float at1 = sQb[1] + dot4(c0,sQk4[2]) + dot4(c1,sQk4[3]);
      at0 = fclip(at0,-5.f,5.f);
      at1 = fclip(at1,-5.f,5.f);
      const float w0 = fsig(at0-at1);
      float4 o0, o1;
      o0.x = fclip(sB1[0]+w0*sBD[0]+0.2f*c0.x, -2.f, 2.f);
      o0.y = fclip(sB1[1]+w0*sBD[1]+0.2f*c0.y, -2.f, 2.f);
      o0.z = fclip(sB1[2]+w0*sBD[2]+0.2f*c0.z, -2.f, 2.f);
      o0.w = fclip(sB1[3]+w0*sBD[3]+0.2f*c0.w, -2.f, 2.f);
      o1.x = fclip(sB1[4]+w0*sBD[4]+0.2f*c1.x, -2.f, 2.f);
      o1.y = fclip(sB1[5]+w0*sBD[5]+0.2f*c1.y, -2.f, 2.f);
      o1.z = fclip(sB1[6]+w0*sBD[6]+0.2f*c1.z, -2.f, 2.f);
      o1.w = fclip(sB1[7]+w0*sBD[7]+0.2f*c1.w, -2.f, 2.f);
      lg0 += dot4(o0,sWoT4[0*8+2*i]) + dot4(o1,sWoT4[0*8+2*i+1]);
      lg1 += dot4(o0,sWoT4[1*8+2*i]) + dot4(o1,sWoT4[1*8+2*i+1]);
      lg2 += dot4(o0,sWoT4[2*8+2*i]) + dot4(o1,sWoT4[2*8+2*i+1]);
    }
    out[(size_t)b*3+0]=lg0;
    out[(size_t)b*3+1]=lg1;
    out[(size_t)b*3+2]=lg2;
  }
}

// ---------------- launch ----------------
extern "C" void kernel_launch(void* const* d_in, const int* in_sizes, int n_in,
                              void* d_out, int out_size, void* d_ws, size_t ws_size,
                              hipStream_t stream)
{
  const float* x      = (const float*)d_in[0];
  const float* We     = (const float*)d_in[1];
  const float* be_    = (const float*)d_in[2];
  const float* adjw   = (const float*)d_in[3];
  const float* Vw     = (const float*)d_in[4];
  const float* Ww     = (const float*)d_in[5];
  const float* gate_w = (const float*)d_in[6];
  const float* gate_b = (const float*)d_in[7];
  const float* hc_w1  = (const float*)d_in[8];
  const float* hc_b1  = (const float*)d_in[9];
  const float* hc_g   = (const float*)d_in[10];
  const float* hc_be  = (const float*)d_in[11];
  const float* hc_w2  = (const float*)d_in[12];
  const float* hc_b2  = (const float*)d_in[13];
  const float* hc_aw  = (const float*)d_in[14];
  const float* hc_ab  = (const float*)d_in[15];
  const float* basis  = (const float*)d_in[16];
  const float* q_w    = (const float*)d_in[17];
  const float* q_b    = (const float*)d_in[18];
  const float* k_w    = (const float*)d_in[19];
  const float* k_b    = (const float*)d_in[20];
  const float* W_out  = (const float*)d_in[21];
  const float* b_out  = (const float*)d_in[22];

  float* ws  = (float*)d_ws;
  float* out = (float*)d_out;
  const int nB = in_sizes[0] / NF;

  setup_k<<<16, 256, 0, stream>>>(We, be_, adjw, Ww, hc_w1, hc_b1,
                                  hc_g, hc_be, hc_w2, hc_b2, hc_aw, hc_ab,
                                  basis, q_w, q_b, k_w, k_b, W_out,
                                  gate_w, gate_b, b_out, ws);

  const int blocks = (nB + 511) / 512;
  double* part = (double*)(ws + WS_PART);

  pass1_k<<<blocks, 256, 0, stream>>>(x, ws, Ww, part, nB);
  pass2_k<<<blocks, 256, 0, stream>>>(x, ws, Vw, part, out, nB, blocks);
}